// Round 8
// baseline (671.982 us; speedup 1.0000x reference)
//
#include <hip/hip_runtime.h>
#include <hip/hip_bf16.h>

#define LRALPHA 0.2f
#define LOG2E 1.4426950408889634f

typedef __attribute__((ext_vector_type(8))) short frag_ab;    // 8 x bf16
typedef __attribute__((ext_vector_type(16))) float f32x16;    // 32x32 acc
typedef float fv4 __attribute__((ext_vector_type(4)));
typedef unsigned int uv4 __attribute__((ext_vector_type(4)));

static __device__ __forceinline__ unsigned short f2bf(float f) {
  __hip_bfloat16 b = __float2bfloat16(f);
  unsigned short u;
  __builtin_memcpy(&u, &b, 2);
  return u;
}

#if __has_builtin(__builtin_amdgcn_exp2f)
#define EXP2F(x) __builtin_amdgcn_exp2f(x)
#else
#define EXP2F(x) exp2f(x)
#endif

// 2 x f32 -> packed 2 x bf16 (RNE), gfx950-native
static __device__ __forceinline__ unsigned cvt_pk_bf16(float lo, float hi) {
  unsigned r;
  asm("v_cvt_pk_bf16_f32 %0, %1, %2" : "=v"(r) : "v"(lo), "v"(hi));
  return r;
}

// 8 w-values -> one in-register A-fragment for mfma_f32_32x32x16_bf16.
// Lane l feeds row (l&31), k = (l>>5)*8 + e. Masked-out: arg=-200 -> exp2=0.
static __device__ __forceinline__ frag_ab make_w8(unsigned mb, fv4 sa, fv4 sb,
                                                  float s1r, float mr, float& zloc) {
  float w[8];
#pragma unroll
  for (int e = 0; e < 8; ++e) {
    const float sv = (e < 4) ? sa[e] : sb[e - 4];
    float ee = s1r + sv;                    // log2 units
    ee = fmaxf(ee, LRALPHA * ee);           // leakyrelu (slope<1)
    const float arg = ((mb >> e) & 1u) ? (ee - mr) : -200.f;  // exp2(-200)=+0
    const float ww = EXP2F(arg);
    zloc += ww;
    w[e] = ww;
  }
  uv4 u;
  u[0] = cvt_pk_bf16(w[0], w[1]);
  u[1] = cvt_pk_bf16(w[2], w[3]);
  u[2] = cvt_pk_bf16(w[4], w[5]);
  u[3] = cvt_pk_bf16(w[6], w[7]);
  frag_ab a;
  __builtin_memcpy(&a, &u, 16);
  return a;
}

// ---------------- Kernel 0: adj (int32, 256 MB) -> TRANSPOSED bitmask
// maskT[jwin (512)][row (8192)] u16: bit e of maskT[jw][r] = adj[r][jw*16+e]>0.
// Transposed so the attn kernel's per-window mask read is ONE cache line
// (lanes read consecutive u16) instead of a 32-line stride-1024B gather.
// Block: 64 rows x 1024 j tile, LDS-staged transpose. Grid 128x8 = 1024.
__global__ __launch_bounds__(256) void gat_adjpack_t(
    const int* __restrict__ adj, unsigned short* __restrict__ maskT) {
  const int rt = blockIdx.x >> 3;  // row tile (64 rows)
  const int jt = blockIdx.x & 7;   // j tile (1024 j)
  const int wave = threadIdx.x >> 6, lane = threadIdx.x & 63;
  __shared__ unsigned short lds[64][64];  // [jwin_local][row_local]

  const size_t base = (size_t)rt * 64 * 8192 + jt * 1024 + wave * 256 + lane;
  for (int r = 0; r < 64; ++r) {
    const int* ap = adj + base + (size_t)r * 8192;
#pragma unroll
    for (int q = 0; q < 4; ++q) {
      int v = __builtin_nontemporal_load(ap + q * 64);
      unsigned long long m = __ballot(v > 0);  // bit l = j (wave*256+q*64+l)
      if (lane < 4)  // u16 e covers j bits [16e,16e+16) of this 64-j word
        lds[wave * 16 + q * 4 + lane][r] = (unsigned short)(m >> (lane * 16));
    }
  }
  __syncthreads();
  // write out coalesced: thread -> (jwin_local = tid>>2, 16-row segment)
  const int jwl = threadIdx.x >> 2, seg = threadIdx.x & 3;
  unsigned short* dst = maskT + (size_t)(jt * 64 + jwl) * 8192 + rt * 64 + seg * 16;
  const uv4* src = (const uv4*)&lds[jwl][seg * 16];
  ((uv4*)dst)[0] = src[0];
  ((uv4*)dst)[1] = src[1];
}

// ---------------- Kernel A: h = X@W (fp32), s1/s2 (pre-scaled by log2 e), hT = bf16(h)^T
__global__ __launch_bounds__(256, 4) void gat_hproj(
    const float* __restrict__ X, const float* __restrict__ W,
    const float* __restrict__ avec,
    float* __restrict__ s1, float* __restrict__ s2,
    unsigned short* __restrict__ hT) {
  const int tid = threadIdx.x;
  const int row0 = blockIdx.x * 16;
  const float* Xb = X + (size_t)row0 * 256;
  const int c = tid;

  float acc[16];
#pragma unroll
  for (int r = 0; r < 16; ++r) acc[r] = 0.f;

  for (int k = 0; k < 256; k += 4) {
    const float w0 = W[(k + 0) * 256 + c];
    const float w1 = W[(k + 1) * 256 + c];
    const float w2 = W[(k + 2) * 256 + c];
    const float w3 = W[(k + 3) * 256 + c];
#pragma unroll
    for (int r = 0; r < 16; ++r) {
      acc[r] = fmaf(Xb[r * 256 + k + 0], w0, acc[r]);
      acc[r] = fmaf(Xb[r * 256 + k + 1], w1, acc[r]);
      acc[r] = fmaf(Xb[r * 256 + k + 2], w2, acc[r]);
      acc[r] = fmaf(Xb[r * 256 + k + 3], w3, acc[r]);
    }
  }

  alignas(16) unsigned short hu[16];
#pragma unroll
  for (int r = 0; r < 16; ++r) hu[r] = f2bf(acc[r]);
  uv4* hdst = (uv4*)(hT + (size_t)c * 8192 + row0);
  hdst[0] = *(const uv4*)&hu[0];
  hdst[1] = *(const uv4*)&hu[8];

  const float a1c = avec[c];
  const float a2c = avec[256 + c];
  const int lane = tid & 63, wave = tid >> 6;
  __shared__ float r1[4][16], r2[4][16];
#pragma unroll
  for (int r = 0; r < 16; ++r) {
    float v1 = acc[r] * a1c;
    float v2 = acc[r] * a2c;
#pragma unroll
    for (int off = 32; off > 0; off >>= 1) {
      v1 += __shfl_down(v1, off);
      v2 += __shfl_down(v2, off);
    }
    if (lane == 0) { r1[wave][r] = v1; r2[wave][r] = v2; }
  }
  __syncthreads();
  if (tid < 16) {
    s1[row0 + tid] = (r1[0][tid] + r1[1][tid] + r1[2][tid] + r1[3][tid]) * LOG2E;
    s2[row0 + tid] = (r2[0][tid] + r2[1][tid] + r2[2][tid] + r2[3][tid]) * LOG2E;
  }
}

// ---------------- Kernel B: barrier-free masked-softmax + P@h partials
// Grid 1024 = 256 rowgroups (32 rows) x 4 j-splits. Block 256 thr = 4 waves:
// wave = (jg = w>>1, fg = w&1). Wave tile: 32 rows x 128 feats x 1024 j.
// A-fragments computed in registers; mask via TRANSPOSED maskT (1 line/window);
// each wave writes its own partial slice (js*2+jg) -> no epilogue LDS/barrier.
__global__ __launch_bounds__(256, 3) void gat_attn_part(
    const unsigned short* __restrict__ maskT, const unsigned short* __restrict__ hT,
    const float* __restrict__ s1, const float* __restrict__ s2,
    float* __restrict__ pacc, float* __restrict__ pZ) {
  const int bid = blockIdx.x;
  const int rowg = bid >> 2, js = bid & 3;
  const int row0 = rowg * 32;
  const int tid = threadIdx.x;
  const int wave = tid >> 6, lane = tid & 63;
  const int fg = wave & 1, jg = wave >> 1;
  const int ln32 = lane & 31, half = lane >> 5;

  __shared__ float wred[4];

  // block-local global max of s2 (bound for exp range)
  float m = -1e30f;
  for (int i = tid; i < 8192; i += 256) m = fmaxf(m, s2[i]);
#pragma unroll
  for (int off = 32; off > 0; off >>= 1) m = fmaxf(m, __shfl_down(m, off));
  if (lane == 0) wred[wave] = m;
  __syncthreads();
  const float s2m = fmaxf(fmaxf(wred[0], wred[1]), fmaxf(wred[2], wred[3]));

  const float s1r = s1[row0 + ln32];                  // this lane's A-row
  const float tmv = s1r + s2m;
  const float mr = tmv >= 0.f ? tmv : LRALPHA * tmv;  // >= row max of lrelu

  const int jbase = (js * 2 + jg) * 1024;             // this wave's j-range
  const int jwb = jbase >> 4;                         // first j-window index
  const unsigned short* mrowT = maskT + row0 + ln32;  // lanes -> consecutive u16
  const unsigned short* hTl = hT + (size_t)(fg * 128 + ln32) * 8192 + half * 8;

  f32x16 acc[4];
#pragma unroll
  for (int ni = 0; ni < 4; ++ni) acc[ni] = (f32x16)(0.f);
  float zloc = 0.f;

  struct LSet { frag_ab B[4]; unsigned short mw; fv4 sa, sb; };
  LSet Sa, Sb;

#define LOADSET(S, T)                                                       \
  {                                                                         \
    const int j0_ = jbase + (T) * 16;                                       \
    int jw_ = jwb + (T);                                                    \
    jw_ = jw_ < 512 ? jw_ : 511; /* clamp overshoot prefetch */             \
    (S).mw = mrowT[(size_t)jw_ * 8192];                                     \
    const float* sp_ = s2 + j0_ + half * 8;                                 \
    (S).sa = *(const fv4*)sp_;                                              \
    (S).sb = *(const fv4*)(sp_ + 4);                                        \
    _Pragma("unroll")                                                       \
    for (int ni = 0; ni < 4; ++ni)                                          \
      (S).B[ni] = *(const frag_ab*)(hTl + (size_t)ni * 32 * 8192 + j0_);    \
  }

#define USESET(S)                                                           \
  {                                                                         \
    const unsigned mb8_ = ((unsigned)(S).mw >> (half * 8)) & 0xffu;         \
    frag_ab A_ = make_w8(mb8_, (S).sa, (S).sb, s1r, mr, zloc);              \
    _Pragma("unroll")                                                       \
    for (int ni = 0; ni < 4; ++ni)                                          \
      acc[ni] = __builtin_amdgcn_mfma_f32_32x32x16_bf16(A_, (S).B[ni],      \
                                                        acc[ni], 0, 0, 0);  \
  }

  LOADSET(Sa, 0);
  for (int t = 0; t < 64; t += 2) {
    LOADSET(Sb, t + 1);
    USESET(Sa);
    LOADSET(Sa, t + 2);  // t=62 -> window 64: clamped/benign in-workspace read
    USESET(Sb);
  }
#undef LOADSET
#undef USESET

  // Z: lane l covers row (l&31), k-half (l>>5); combine halves
  const float zrow = zloc + __shfl_xor(zloc, 32);

  // write this wave's partial slice directly (no block combine, no barrier)
  // C/D layout (32x32): col(f-off)=lane&31, row=(reg&3)+8*(reg>>2)+4*(lane>>5)
  const int slice = js * 2 + jg;
  float* paccb = pacc + ((size_t)slice * 8192 + row0) * 256;
#pragma unroll
  for (int ni = 0; ni < 4; ++ni)
#pragma unroll
    for (int reg = 0; reg < 16; ++reg) {
      const int grow = (reg & 3) + 8 * (reg >> 2) + 4 * half;
      const int f = fg * 128 + ni * 32 + ln32;
      __builtin_nontemporal_store(acc[ni][reg], paccb + (size_t)grow * 256 + f);
    }
  if (fg == 0 && lane < 32)
    pZ[slice * 8192 + row0 + lane] = zrow;
}

// ---------------- Kernel D: combine 8 partial slices, divide by Z, elu
__global__ __launch_bounds__(256) void gat_combine(
    const float* __restrict__ pacc, const float* __restrict__ pZ,
    float* __restrict__ out) {
  const int idx = blockIdx.x * 256 + threadIdx.x;  // float4 index, 524288 total
  const int row = idx >> 6;
  float z = 0.f;
#pragma unroll
  for (int s = 0; s < 8; ++s) z += pZ[s * 8192 + row];
  const float invz = 1.f / z;
  const size_t PSTRIDE = (size_t)8192 * 256;
  fv4 n = {0.f, 0.f, 0.f, 0.f};
#pragma unroll
  for (int s = 0; s < 8; ++s) {
    const fv4 v = *(const fv4*)(pacc + s * PSTRIDE + (size_t)idx * 4);
#pragma unroll
    for (int e = 0; e < 4; ++e) n[e] += v[e];
  }
  fv4 o;
#pragma unroll
  for (int e = 0; e < 4; ++e) {
    const float vv = n[e] * invz;
    o[e] = vv > 0.f ? vv : expm1f(vv);
  }
  *(fv4*)(out + (size_t)idx * 4) = o;
}

extern "C" void kernel_launch(void* const* d_in, const int* in_sizes, int n_in,
                              void* d_out, int out_size, void* d_ws, size_t ws_size,
                              hipStream_t stream) {
  const float* X = (const float*)d_in[0];
  const int* adj = (const int*)d_in[1];
  const float* W = (const float*)d_in[2];
  const float* avec = (const float*)d_in[3];
  float* out = (float*)d_out;

  float* wsf = (float*)d_ws;
  float* s1 = wsf;                          // 8192 floats
  float* s2 = wsf + 8192;                   // 8192 floats
  float* pZ = wsf + 16384;                  // 8*8192 = 65536 floats
  float* pacc = wsf + 81920;                // 8*8192*256 = 16,777,216 floats (64 MB)
  unsigned short* hT = (unsigned short*)(wsf + 81920 + 16777216);     // 4 MB
  unsigned short* maskT =
      (unsigned short*)(wsf + 81920 + 16777216 + 1048576);            // 8 MB

  hipLaunchKernelGGL(gat_adjpack_t, dim3(1024), dim3(256), 0, stream, adj, maskT);
  hipLaunchKernelGGL(gat_hproj, dim3(512), dim3(256), 0, stream, X, W, avec, s1, s2, hT);
  hipLaunchKernelGGL(gat_attn_part, dim3(1024), dim3(256), 0, stream,
                     maskT, hT, s1, s2, pacc, pZ);
  hipLaunchKernelGGL(gat_combine, dim3(2048), dim3(256), 0, stream, pacc, pZ, out);
}

// Round 9
// 628.955 us; speedup vs baseline: 1.0684x; 1.0684x over previous
//
#include <hip/hip_runtime.h>
#include <hip/hip_bf16.h>

#define LRALPHA 0.2f
#define LOG2E 1.4426950408889634f

typedef __attribute__((ext_vector_type(8))) short frag_ab;    // 8 x bf16
typedef __attribute__((ext_vector_type(16))) float f32x16;    // 32x32 acc
typedef float fv4 __attribute__((ext_vector_type(4)));
typedef unsigned int uv4 __attribute__((ext_vector_type(4)));

static __device__ __forceinline__ unsigned short f2bf(float f) {
  __hip_bfloat16 b = __float2bfloat16(f);
  unsigned short u;
  __builtin_memcpy(&u, &b, 2);
  return u;
}

#if __has_builtin(__builtin_amdgcn_exp2f)
#define EXP2F(x) __builtin_amdgcn_exp2f(x)
#else
#define EXP2F(x) exp2f(x)
#endif

// 2 x f32 -> packed 2 x bf16 (RNE), gfx950-native
static __device__ __forceinline__ unsigned cvt_pk_bf16(float lo, float hi) {
  unsigned r;
  asm("v_cvt_pk_bf16_f32 %0, %1, %2" : "=v"(r) : "v"(lo), "v"(hi));
  return r;
}

// 8 w-values -> one in-register A-fragment for mfma_f32_32x32x16_bf16.
// Lane l feeds row (l&31), k = (l>>5)*8 + e. Masked-out: arg=-200 -> exp2=0.
static __device__ __forceinline__ frag_ab make_w8(unsigned mb, fv4 sa, fv4 sb,
                                                  float s1r, float mr, float& zloc) {
  float w[8];
#pragma unroll
  for (int e = 0; e < 8; ++e) {
    const float sv = (e < 4) ? sa[e] : sb[e - 4];
    float ee = s1r + sv;                    // log2 units
    ee = fmaxf(ee, LRALPHA * ee);           // leakyrelu (slope<1)
    const float arg = ((mb >> e) & 1u) ? (ee - mr) : -200.f;  // exp2(-200)=+0
    const float ww = EXP2F(arg);
    zloc += ww;
    w[e] = ww;
  }
  uv4 u;
  u[0] = cvt_pk_bf16(w[0], w[1]);
  u[1] = cvt_pk_bf16(w[2], w[3]);
  u[2] = cvt_pk_bf16(w[4], w[5]);
  u[3] = cvt_pk_bf16(w[6], w[7]);
  frag_ab a;
  __builtin_memcpy(&a, &u, 16);
  return a;
}

// ---------------- Kernel 0: adj (int32, 256 MB) -> TRANSPOSED bitmask
// maskT[jwin (512)][row (8192)] u16: bit e of maskT[jw][r] = adj[r][jw*16+e]>0.
__global__ __launch_bounds__(256) void gat_adjpack_t(
    const int* __restrict__ adj, unsigned short* __restrict__ maskT) {
  const int rt = blockIdx.x >> 3;  // row tile (64 rows)
  const int jt = blockIdx.x & 7;   // j tile (1024 j)
  const int wave = threadIdx.x >> 6, lane = threadIdx.x & 63;
  __shared__ unsigned short lds[64][64];  // [jwin_local][row_local]

  const size_t base = (size_t)rt * 64 * 8192 + jt * 1024 + wave * 256 + lane;
  for (int r = 0; r < 64; ++r) {
    const int* ap = adj + base + (size_t)r * 8192;
#pragma unroll
    for (int q = 0; q < 4; ++q) {
      int v = __builtin_nontemporal_load(ap + q * 64);
      unsigned long long m = __ballot(v > 0);  // bit l = j (wave*256+q*64+l)
      if (lane < 4)  // u16 e covers j bits [16e,16e+16) of this 64-j word
        lds[wave * 16 + q * 4 + lane][r] = (unsigned short)(m >> (lane * 16));
    }
  }
  __syncthreads();
  // write out coalesced: thread -> (jwin_local = tid>>2, 16-row segment)
  const int jwl = threadIdx.x >> 2, seg = threadIdx.x & 3;
  unsigned short* dst = maskT + (size_t)(jt * 64 + jwl) * 8192 + rt * 64 + seg * 16;
  const uv4* src = (const uv4*)&lds[jwl][seg * 16];
  ((uv4*)dst)[0] = src[0];
  ((uv4*)dst)[1] = src[1];
}

// ---------------- Kernel A: h = X@W (fp32), s1/s2 (pre-scaled by log2 e),
// h stored as hB in MFMA-B-FRAGMENT layout:
//   hB[jw (512)][fb (8)][lane (64)][e (8)] bf16, where the B-frag for
//   window jw, feature-block fb at lane l = h[jw*16 + (l>>5)*8+e][fb*32+(l&31)].
// One wave-load of 64 consecutive lanes*16B = fully coalesced 1 KB.
__global__ __launch_bounds__(256, 4) void gat_hproj(
    const float* __restrict__ X, const float* __restrict__ W,
    const float* __restrict__ avec,
    float* __restrict__ s1, float* __restrict__ s2,
    unsigned short* __restrict__ hB) {
  const int tid = threadIdx.x;
  const int row0 = blockIdx.x * 16;  // 16 j-rows = exactly one window
  const float* Xb = X + (size_t)row0 * 256;
  const int c = tid;

  float acc[16];
#pragma unroll
  for (int r = 0; r < 16; ++r) acc[r] = 0.f;

  for (int k = 0; k < 256; k += 4) {
    const float w0 = W[(k + 0) * 256 + c];
    const float w1 = W[(k + 1) * 256 + c];
    const float w2 = W[(k + 2) * 256 + c];
    const float w3 = W[(k + 3) * 256 + c];
#pragma unroll
    for (int r = 0; r < 16; ++r) {
      acc[r] = fmaf(Xb[r * 256 + k + 0], w0, acc[r]);
      acc[r] = fmaf(Xb[r * 256 + k + 1], w1, acc[r]);
      acc[r] = fmaf(Xb[r * 256 + k + 2], w2, acc[r]);
      acc[r] = fmaf(Xb[r * 256 + k + 3], w3, acc[r]);
    }
  }

  // write B-frag layout: thread c -> window jw=row0/16, fb=c>>5, col=c&31.
  // r (=jpos) 0..7 -> lane (c&31), e=r; r 8..15 -> lane 32+(c&31), e=r-8.
  alignas(16) unsigned short hu[16];
#pragma unroll
  for (int r = 0; r < 16; ++r) hu[r] = f2bf(acc[r]);
  const int jw = row0 >> 4, fb = c >> 5, c31 = c & 31;
  unsigned short* hbase = hB + ((size_t)jw * 8 + fb) * 64 * 8;
  *(uv4*)(hbase + (size_t)c31 * 8) = *(const uv4*)&hu[0];         // half 0
  *(uv4*)(hbase + (size_t)(32 + c31) * 8) = *(const uv4*)&hu[8];  // half 1

  // s1/s2: reduce acc[r]*a over 256 threads (=columns); scaled by log2(e).
  const float a1c = avec[c];
  const float a2c = avec[256 + c];
  const int lane = tid & 63, wave = tid >> 6;
  __shared__ float r1[4][16], r2[4][16];
#pragma unroll
  for (int r = 0; r < 16; ++r) {
    float v1 = acc[r] * a1c;
    float v2 = acc[r] * a2c;
#pragma unroll
    for (int off = 32; off > 0; off >>= 1) {
      v1 += __shfl_down(v1, off);
      v2 += __shfl_down(v2, off);
    }
    if (lane == 0) { r1[wave][r] = v1; r2[wave][r] = v2; }
  }
  __syncthreads();
  if (tid < 16) {
    s1[row0 + tid] = (r1[0][tid] + r1[1][tid] + r1[2][tid] + r1[3][tid]) * LOG2E;
    s2[row0 + tid] = (r2[0][tid] + r2[1][tid] + r2[2][tid] + r2[3][tid]) * LOG2E;
  }
}

// ---------------- Kernel B: barrier-free masked-softmax + P@h partials
// Grid 1024 = 256 rowgroups (32 rows) x 4 j-splits. Block 256 thr = 4 waves:
// wave = (jg = w>>1, fg = w&1). Wave tile: 32 rows x 128 feats x 1024 j.
// A-frags computed in registers; mask via transposed maskT (1 line/window);
// B-frags via hB fragment-layout (1 KB coalesced per load — the R8 fix:
// hT [f][j] layout was a 32-cache-line gather per B-load, 4x per window).
__global__ __launch_bounds__(256, 4) void gat_attn_part(
    const unsigned short* __restrict__ maskT, const unsigned short* __restrict__ hB,
    const float* __restrict__ s1, const float* __restrict__ s2,
    float* __restrict__ pacc, float* __restrict__ pZ) {
  const int bid = blockIdx.x;
  const int rowg = bid >> 2, js = bid & 3;
  const int row0 = rowg * 32;
  const int tid = threadIdx.x;
  const int wave = tid >> 6, lane = tid & 63;
  const int fg = wave & 1, jg = wave >> 1;
  const int ln32 = lane & 31, half = lane >> 5;

  __shared__ float wred[4];

  // block-local global max of s2 (bound for exp range)
  float m = -1e30f;
  for (int i = tid; i < 8192; i += 256) m = fmaxf(m, s2[i]);
#pragma unroll
  for (int off = 32; off > 0; off >>= 1) m = fmaxf(m, __shfl_down(m, off));
  if (lane == 0) wred[wave] = m;
  __syncthreads();
  const float s2m = fmaxf(fmaxf(wred[0], wred[1]), fmaxf(wred[2], wred[3]));

  const float s1r = s1[row0 + ln32];                  // this lane's A-row
  const float tmv = s1r + s2m;
  const float mr = tmv >= 0.f ? tmv : LRALPHA * tmv;  // >= row max of lrelu

  const int jbase = (js * 2 + jg) * 1024;             // this wave's j-range
  const int jwb = jbase >> 4;                         // first j-window index
  const unsigned short* mrowT = maskT + row0 + ln32;  // lanes -> consecutive u16

  f32x16 acc[4];
#pragma unroll
  for (int ni = 0; ni < 4; ++ni) acc[ni] = (f32x16)(0.f);
  float zloc = 0.f;

  struct LSet { frag_ab B[4]; unsigned short mw; fv4 sa, sb; };
  LSet Sa, Sb;

#define LOADSET(S, T)                                                         \
  {                                                                           \
    const int j0_ = jbase + (T) * 16;                                         \
    int jw_ = jwb + (T);                                                      \
    jw_ = jw_ < 512 ? jw_ : 511; /* clamp overshoot prefetch */               \
    (S).mw = mrowT[(size_t)jw_ * 8192];                                       \
    const float* sp_ = s2 + j0_ + half * 8;                                   \
    (S).sa = *(const fv4*)sp_;                                                \
    (S).sb = *(const fv4*)(sp_ + 4);                                          \
    _Pragma("unroll")                                                         \
    for (int ni = 0; ni < 4; ++ni)                                            \
      (S).B[ni] = *(const frag_ab*)(hB +                                      \
          (((size_t)jw_ * 8 + fg * 4 + ni) * 64 + lane) * 8);                 \
  }

#define USESET(S)                                                             \
  {                                                                           \
    const unsigned mb8_ = ((unsigned)(S).mw >> (half * 8)) & 0xffu;           \
    frag_ab A_ = make_w8(mb8_, (S).sa, (S).sb, s1r, mr, zloc);                \
    _Pragma("unroll")                                                         \
    for (int ni = 0; ni < 4; ++ni)                                            \
      acc[ni] = __builtin_amdgcn_mfma_f32_32x32x16_bf16(A_, (S).B[ni],        \
                                                        acc[ni], 0, 0, 0);    \
  }

  LOADSET(Sa, 0);
  for (int t = 0; t < 64; t += 2) {
    LOADSET(Sb, t + 1);
    USESET(Sa);
    LOADSET(Sa, t + 2);  // t=62 -> window 64: clamped/benign in-workspace read
    USESET(Sb);
  }
#undef LOADSET
#undef USESET

  // Z: lane l covers row (l&31), k-half (l>>5); combine halves
  const float zrow = zloc + __shfl_xor(zloc, 32);

  // write this wave's partial slice directly (no block combine, no barrier)
  // C/D layout (32x32): col(f-off)=lane&31, row=(reg&3)+8*(reg>>2)+4*(lane>>5)
  const int slice = js * 2 + jg;
  float* paccb = pacc + ((size_t)slice * 8192 + row0) * 256;
#pragma unroll
  for (int ni = 0; ni < 4; ++ni)
#pragma unroll
    for (int reg = 0; reg < 16; ++reg) {
      const int grow = (reg & 3) + 8 * (reg >> 2) + 4 * half;
      const int f = fg * 128 + ni * 32 + ln32;
      __builtin_nontemporal_store(acc[ni][reg], paccb + (size_t)grow * 256 + f);
    }
  if (fg == 0 && lane < 32)
    pZ[slice * 8192 + row0 + lane] = zrow;
}

// ---------------- Kernel D: combine 8 partial slices, divide by Z, elu
__global__ __launch_bounds__(256) void gat_combine(
    const float* __restrict__ pacc, const float* __restrict__ pZ,
    float* __restrict__ out) {
  const int idx = blockIdx.x * 256 + threadIdx.x;  // float4 index, 524288 total
  const int row = idx >> 6;
  float z = 0.f;
#pragma unroll
  for (int s = 0; s < 8; ++s) z += pZ[s * 8192 + row];
  const float invz = 1.f / z;
  const size_t PSTRIDE = (size_t)8192 * 256;
  fv4 n = {0.f, 0.f, 0.f, 0.f};
#pragma unroll
  for (int s = 0; s < 8; ++s) {
    const fv4 v = *(const fv4*)(pacc + s * PSTRIDE + (size_t)idx * 4);
#pragma unroll
    for (int e = 0; e < 4; ++e) n[e] += v[e];
  }
  fv4 o;
#pragma unroll
  for (int e = 0; e < 4; ++e) {
    const float vv = n[e] * invz;
    o[e] = vv > 0.f ? vv : expm1f(vv);
  }
  *(fv4*)(out + (size_t)idx * 4) = o;
}

extern "C" void kernel_launch(void* const* d_in, const int* in_sizes, int n_in,
                              void* d_out, int out_size, void* d_ws, size_t ws_size,
                              hipStream_t stream) {
  const float* X = (const float*)d_in[0];
  const int* adj = (const int*)d_in[1];
  const float* W = (const float*)d_in[2];
  const float* avec = (const float*)d_in[3];
  float* out = (float*)d_out;

  float* wsf = (float*)d_ws;
  float* s1 = wsf;                          // 8192 floats
  float* s2 = wsf + 8192;                   // 8192 floats
  float* pZ = wsf + 16384;                  // 8*8192 = 65536 floats
  float* pacc = wsf + 81920;                // 8*8192*256 = 16,777,216 floats (64 MB)
  unsigned short* hB = (unsigned short*)(wsf + 81920 + 16777216);     // 4 MB
  unsigned short* maskT =
      (unsigned short*)(wsf + 81920 + 16777216 + 1048576);            // 8 MB

  hipLaunchKernelGGL(gat_adjpack_t, dim3(1024), dim3(256), 0, stream, adj, maskT);
  hipLaunchKernelGGL(gat_hproj, dim3(512), dim3(256), 0, stream, X, W, avec, s1, s2, hB);
  hipLaunchKernelGGL(gat_attn_part, dim3(1024), dim3(256), 0, stream,
                     maskT, hB, s1, s2, pacc, pZ);
  hipLaunchKernelGGL(gat_combine, dim3(2048), dim3(256), 0, stream, pacc, pZ, out);
}